// Round 7
// baseline (487.485 us; speedup 1.0000x reference)
//
#include <hip/hip_runtime.h>

// Separable 3D Gaussian blur (sigma=1, truncate=3 -> 7 taps), SAME zero padding.
// (N=2, D=160, H=160, W=160, C=4) float32 == float4 over C.
// Round 7: round-6 grouped structure with occupancy fixes:
//  - SINGLE-buffered raw and wb (hazards covered by the two lgkm barriers:
//    raw reads drain at B before next top-of-loop write; wb reads drain at A
//    before next W-blur write) -> LDS 39.4 -> 25.3 KB (6 blocks/CU cap).
//  - CHUNK 16 -> 10 -> grid 1600 blocks = 6.25/CU, matches capacity.
//  - launch_bounds(256,6): VGPR cap 85 (used 64 last round).
// Tile 16(H) x 32(W); W-blur: 176 workers x (10 raw reads -> 4 wb outputs);
// H-blur: 256 threads x (8 wb reads -> 2 outputs, dual 7-deep D-rings);
// register prefetch one slice ahead rides across the lgkm-only barriers.

#define THT 16             // tile height (H outputs)
#define TWT 32             // tile width  (W outputs)
#define CHUNK 10           // output D-slices per block
#define DIM 160
#define SLICE (DIM * DIM)  // float4 elements per (D) slice
#define RAWN (22 * 38)     // staged halo f4 per slice = 836

#define W0 0.004433048f
#define W1 0.054005582f
#define W2 0.242036229f
#define W3 0.399050300f

__device__ __forceinline__ float4 blur7(float4 a0, float4 a1, float4 a2, float4 a3,
                                        float4 a4, float4 a5, float4 a6) {
    float4 r;
    r.x = W0 * (a0.x + a6.x) + W1 * (a1.x + a5.x) + W2 * (a2.x + a4.x) + W3 * a3.x;
    r.y = W0 * (a0.y + a6.y) + W1 * (a1.y + a5.y) + W2 * (a2.y + a4.y) + W3 * a3.y;
    r.z = W0 * (a0.z + a6.z) + W1 * (a1.z + a5.z) + W2 * (a2.z + a4.z) + W3 * a3.z;
    r.w = W0 * (a0.w + a6.w) + W1 * (a1.w + a5.w) + W2 * (a2.w + a4.w) + W3 * a3.w;
    return r;
}

// Workgroup barrier with LDS visibility but NO vmcnt(0) drain -> prefetched
// global loads stay in flight across it.
__device__ __forceinline__ void lds_barrier() {
    asm volatile("s_waitcnt lgkmcnt(0)" ::: "memory");
    __builtin_amdgcn_s_barrier();
}

__global__ __launch_bounds__(256, 6)
void gauss3d_fused(const float4* __restrict__ in, float4* __restrict__ out) {
    // decode block: (tw, th, chunk, n); 5 W-tiles, 10 H-tiles, 16 chunks
    int bid = blockIdx.x;
    const int tw    = bid % (DIM / TWT);   bid /= (DIM / TWT);
    const int th    = bid % (DIM / THT);   bid /= (DIM / THT);
    const int chunk = bid % (DIM / CHUNK); bid /= (DIM / CHUNK);
    const int n     = bid;

    const int h0 = th * THT;
    const int w0 = tw * TWT;
    const int d0 = chunk * CHUNK;

    __shared__ float4 raw[22][39];  // halo 22(H) x 38(W), odd col pad
    __shared__ float4 wb[22][33];   // W-blurred 22 x 32, odd col pad

    const int tid = threadIdx.x;
    const size_t nbase = (size_t)n * DIM * SLICE;
    const float4 z = make_float4(0.f, 0.f, 0.f, 0.f);

    // ---- stage constants: 836 halo f4 over 256 threads (<=4 slots) ----
    int  soff[4], rbidx[4];
    bool sok[4], shas[4];
    #pragma unroll
    for (int s = 0; s < 4; ++s) {
        const int i = tid + 256 * s;
        const bool has = (i < RAWN);
        const int rr = has ? (i / 38) : 0, cc = has ? (i % 38) : 0;
        const int gh = h0 + rr - 3, gw = w0 + cc - 3;
        const bool ok = has && gh >= 0 && gh < DIM && gw >= 0 && gw < DIM;
        soff[s]  = ok ? (gh * DIM + gw) : 0;
        sok[s]   = ok;
        shas[s]  = has;
        rbidx[s] = rr * 39 + cc;
    }

    // ---- W-blur worker constants: 176 workers = 22 rows x 8 groups of 4 ----
    const bool isW = (tid < 176);
    const int wr  = tid >> 3;        // 0..21
    const int wc0 = (tid & 7) * 4;   // 0,4,...,28

    // ---- H-blur constants: 256 threads = 8 H-pairs x 32 cols ----
    const int hp = tid >> 5;         // 0..7 -> output rows 2hp, 2hp+1
    const int lw = tid & 31;         // 0..31

    float4 pf0, pf1, pf2, pf3;
    float4 a0 = z, a1 = z, a2 = z, a3 = z, a4 = z, a5 = z, a6 = z;  // ring row 2hp
    float4 b0 = z, b1 = z, b2 = z, b3 = z, b4 = z, b5 = z, b6 = z;  // ring row 2hp+1

#define PREFETCH(DSL)                                                        \
    do {                                                                     \
        const int _d = (DSL);                                                \
        const bool _inr = (_d >= 0) && (_d < DIM);                           \
        const float4* _s = in + nbase + (size_t)(_inr ? _d : 0) * SLICE;     \
        pf0 = (_inr && sok[0]) ? _s[soff[0]] : z;                            \
        pf1 = (_inr && sok[1]) ? _s[soff[1]] : z;                            \
        pf2 = (_inr && sok[2]) ? _s[soff[2]] : z;                            \
        pf3 = (_inr && sok[3]) ? _s[soff[3]] : z;                            \
    } while (0)

    PREFETCH(d0 - 3);

    for (int din = d0 - 3; din <= d0 + CHUNK + 2; ++din) {
        // 1) commit prefetched slice into raw (prev W-blur reads drained at
        //    the previous iteration's barrier B -> single buffer is safe)
        {
            float4* rb = &raw[0][0];
            rb[rbidx[0]] = pf0;
            rb[rbidx[1]] = pf1;
            rb[rbidx[2]] = pf2;
            if (shas[3]) rb[rbidx[3]] = pf3;
        }

        // 2) issue next slice's loads; in flight across both barriers
        PREFETCH(din + 1);

        lds_barrier();  // A: raw visible; prev H-blur reads of wb drained

        // 3) W-blur: 176 workers, 10 raw reads -> 4 wb outputs each
        if (isW) {
            float4 rv0 = raw[wr][wc0 + 0];
            float4 rv1 = raw[wr][wc0 + 1];
            float4 rv2 = raw[wr][wc0 + 2];
            float4 rv3 = raw[wr][wc0 + 3];
            float4 rv4 = raw[wr][wc0 + 4];
            float4 rv5 = raw[wr][wc0 + 5];
            float4 rv6 = raw[wr][wc0 + 6];
            float4 rv7 = raw[wr][wc0 + 7];
            float4 rv8 = raw[wr][wc0 + 8];
            float4 rv9 = raw[wr][wc0 + 9];
            wb[wr][wc0 + 0] = blur7(rv0, rv1, rv2, rv3, rv4, rv5, rv6);
            wb[wr][wc0 + 1] = blur7(rv1, rv2, rv3, rv4, rv5, rv6, rv7);
            wb[wr][wc0 + 2] = blur7(rv2, rv3, rv4, rv5, rv6, rv7, rv8);
            wb[wr][wc0 + 3] = blur7(rv3, rv4, rv5, rv6, rv7, rv8, rv9);
        }

        lds_barrier();  // B: wb visible; raw reads drained (next top rewrites)

        // 4) H-blur pair: 8 wb reads -> 2 new ring values
        {
            float4 c0 = wb[2 * hp + 0][lw];
            float4 c1 = wb[2 * hp + 1][lw];
            float4 c2 = wb[2 * hp + 2][lw];
            float4 c3 = wb[2 * hp + 3][lw];
            float4 c4 = wb[2 * hp + 4][lw];
            float4 c5 = wb[2 * hp + 5][lw];
            float4 c6 = wb[2 * hp + 6][lw];
            float4 c7 = wb[2 * hp + 7][lw];
            float4 va = blur7(c0, c1, c2, c3, c4, c5, c6);
            float4 vb = blur7(c1, c2, c3, c4, c5, c6, c7);
            a0 = a1; a1 = a2; a2 = a3; a3 = a4; a4 = a5; a5 = a6; a6 = va;
            b0 = b1; b1 = b2; b2 = b3; b3 = b4; b4 = b5; b5 = b6; b6 = vb;
        }

        const int dout = din - 3;
        if (dout >= d0) {   // dout < d0+CHUNK by loop bound
            float4 oa = blur7(a0, a1, a2, a3, a4, a5, a6);
            float4 ob = blur7(b0, b1, b2, b3, b4, b5, b6);
            const size_t base = nbase + (size_t)dout * SLICE;
            out[base + (size_t)(h0 + 2 * hp + 0) * DIM + (w0 + lw)] = oa;
            out[base + (size_t)(h0 + 2 * hp + 1) * DIM + (w0 + lw)] = ob;
        }
    }
#undef PREFETCH
}

extern "C" void kernel_launch(void* const* d_in, const int* in_sizes, int n_in,
                              void* d_out, int out_size, void* d_ws, size_t ws_size,
                              hipStream_t stream) {
    const float4* in = (const float4*)d_in[0];
    float4* out = (float4*)d_out;
    const int nblocks =
        2 * (DIM / THT) * (DIM / TWT) * (DIM / CHUNK);  // 2*10*5*16 = 1600
    gauss3d_fused<<<nblocks, 256, 0, stream>>>(in, out);
}

// Round 8
// 89.938 us; speedup vs baseline: 5.4202x; 5.4202x over previous
//
#include <hip/hip_runtime.h>

// Separable 3D Gaussian blur (sigma=1, truncate=3 -> 7 taps), SAME zero padding.
// (N=2, D=160, H=160, W=160, C=4) float32 == float4 over C.
// Round 8 = round 7 with launch_bounds reverted to (256,4).
//   Round 7's (256,6) capped VGPRs at 85 < ~95 live regs (dual rings 56 +
//   prefetch 16 + consts) -> scratch spills -> WRITE_SIZE 133MB -> 1.08GB.
//   Occupancy comes from LDS (25.3KB -> 6 blocks/CU) and grid (1600 blocks
//   = 6.25/CU), NOT from the register cap.
// Tile 16(H) x 32(W), CHUNK=10; single-buffered raw+wb (hazards covered by
// the two lgkm-only barriers); W-blur: 176 workers x (10 raw reads -> 4 wb
// outputs); H-blur: 256 threads x (8 wb reads -> 2 outputs, dual 7-deep
// D-rings); register prefetch one slice ahead rides across barriers.

#define THT 16             // tile height (H outputs)
#define TWT 32             // tile width  (W outputs)
#define CHUNK 10           // output D-slices per block
#define DIM 160
#define SLICE (DIM * DIM)  // float4 elements per (D) slice
#define RAWN (22 * 38)     // staged halo f4 per slice = 836

#define W0 0.004433048f
#define W1 0.054005582f
#define W2 0.242036229f
#define W3 0.399050300f

__device__ __forceinline__ float4 blur7(float4 a0, float4 a1, float4 a2, float4 a3,
                                        float4 a4, float4 a5, float4 a6) {
    float4 r;
    r.x = W0 * (a0.x + a6.x) + W1 * (a1.x + a5.x) + W2 * (a2.x + a4.x) + W3 * a3.x;
    r.y = W0 * (a0.y + a6.y) + W1 * (a1.y + a5.y) + W2 * (a2.y + a4.y) + W3 * a3.y;
    r.z = W0 * (a0.z + a6.z) + W1 * (a1.z + a5.z) + W2 * (a2.z + a4.z) + W3 * a3.z;
    r.w = W0 * (a0.w + a6.w) + W1 * (a1.w + a5.w) + W2 * (a2.w + a4.w) + W3 * a3.w;
    return r;
}

// Workgroup barrier with LDS visibility but NO vmcnt(0) drain -> prefetched
// global loads stay in flight across it.
__device__ __forceinline__ void lds_barrier() {
    asm volatile("s_waitcnt lgkmcnt(0)" ::: "memory");
    __builtin_amdgcn_s_barrier();
}

__global__ __launch_bounds__(256, 4)
void gauss3d_fused(const float4* __restrict__ in, float4* __restrict__ out) {
    // decode block: (tw, th, chunk, n); 5 W-tiles, 10 H-tiles, 16 chunks
    int bid = blockIdx.x;
    const int tw    = bid % (DIM / TWT);   bid /= (DIM / TWT);
    const int th    = bid % (DIM / THT);   bid /= (DIM / THT);
    const int chunk = bid % (DIM / CHUNK); bid /= (DIM / CHUNK);
    const int n     = bid;

    const int h0 = th * THT;
    const int w0 = tw * TWT;
    const int d0 = chunk * CHUNK;

    __shared__ float4 raw[22][39];  // halo 22(H) x 38(W), odd col pad
    __shared__ float4 wb[22][33];   // W-blurred 22 x 32, odd col pad

    const int tid = threadIdx.x;
    const size_t nbase = (size_t)n * DIM * SLICE;
    const float4 z = make_float4(0.f, 0.f, 0.f, 0.f);

    // ---- stage constants: 836 halo f4 over 256 threads (<=4 slots) ----
    int  soff[4], rbidx[4];
    bool sok[4], shas[4];
    #pragma unroll
    for (int s = 0; s < 4; ++s) {
        const int i = tid + 256 * s;
        const bool has = (i < RAWN);
        const int rr = has ? (i / 38) : 0, cc = has ? (i % 38) : 0;
        const int gh = h0 + rr - 3, gw = w0 + cc - 3;
        const bool ok = has && gh >= 0 && gh < DIM && gw >= 0 && gw < DIM;
        soff[s]  = ok ? (gh * DIM + gw) : 0;
        sok[s]   = ok;
        shas[s]  = has;
        rbidx[s] = rr * 39 + cc;
    }

    // ---- W-blur worker constants: 176 workers = 22 rows x 8 groups of 4 ----
    const bool isW = (tid < 176);
    const int wr  = tid >> 3;        // 0..21
    const int wc0 = (tid & 7) * 4;   // 0,4,...,28

    // ---- H-blur constants: 256 threads = 8 H-pairs x 32 cols ----
    const int hp = tid >> 5;         // 0..7 -> output rows 2hp, 2hp+1
    const int lw = tid & 31;         // 0..31

    float4 pf0, pf1, pf2, pf3;
    float4 a0 = z, a1 = z, a2 = z, a3 = z, a4 = z, a5 = z, a6 = z;  // ring row 2hp
    float4 b0 = z, b1 = z, b2 = z, b3 = z, b4 = z, b5 = z, b6 = z;  // ring row 2hp+1

#define PREFETCH(DSL)                                                        \
    do {                                                                     \
        const int _d = (DSL);                                                \
        const bool _inr = (_d >= 0) && (_d < DIM);                           \
        const float4* _s = in + nbase + (size_t)(_inr ? _d : 0) * SLICE;     \
        pf0 = (_inr && sok[0]) ? _s[soff[0]] : z;                            \
        pf1 = (_inr && sok[1]) ? _s[soff[1]] : z;                            \
        pf2 = (_inr && sok[2]) ? _s[soff[2]] : z;                            \
        pf3 = (_inr && sok[3]) ? _s[soff[3]] : z;                            \
    } while (0)

    PREFETCH(d0 - 3);

    for (int din = d0 - 3; din <= d0 + CHUNK + 2; ++din) {
        // 1) commit prefetched slice into raw (prev W-blur reads drained at
        //    the previous iteration's barrier B -> single buffer is safe)
        {
            float4* rb = &raw[0][0];
            rb[rbidx[0]] = pf0;
            rb[rbidx[1]] = pf1;
            rb[rbidx[2]] = pf2;
            if (shas[3]) rb[rbidx[3]] = pf3;
        }

        // 2) issue next slice's loads; in flight across both barriers
        PREFETCH(din + 1);

        lds_barrier();  // A: raw visible; prev H-blur reads of wb drained

        // 3) W-blur: 176 workers, 10 raw reads -> 4 wb outputs each
        if (isW) {
            float4 rv0 = raw[wr][wc0 + 0];
            float4 rv1 = raw[wr][wc0 + 1];
            float4 rv2 = raw[wr][wc0 + 2];
            float4 rv3 = raw[wr][wc0 + 3];
            float4 rv4 = raw[wr][wc0 + 4];
            float4 rv5 = raw[wr][wc0 + 5];
            float4 rv6 = raw[wr][wc0 + 6];
            float4 rv7 = raw[wr][wc0 + 7];
            float4 rv8 = raw[wr][wc0 + 8];
            float4 rv9 = raw[wr][wc0 + 9];
            wb[wr][wc0 + 0] = blur7(rv0, rv1, rv2, rv3, rv4, rv5, rv6);
            wb[wr][wc0 + 1] = blur7(rv1, rv2, rv3, rv4, rv5, rv6, rv7);
            wb[wr][wc0 + 2] = blur7(rv2, rv3, rv4, rv5, rv6, rv7, rv8);
            wb[wr][wc0 + 3] = blur7(rv3, rv4, rv5, rv6, rv7, rv8, rv9);
        }

        lds_barrier();  // B: wb visible; raw reads drained (next top rewrites)

        // 4) H-blur pair: 8 wb reads -> 2 new ring values
        {
            float4 c0 = wb[2 * hp + 0][lw];
            float4 c1 = wb[2 * hp + 1][lw];
            float4 c2 = wb[2 * hp + 2][lw];
            float4 c3 = wb[2 * hp + 3][lw];
            float4 c4 = wb[2 * hp + 4][lw];
            float4 c5 = wb[2 * hp + 5][lw];
            float4 c6 = wb[2 * hp + 6][lw];
            float4 c7 = wb[2 * hp + 7][lw];
            float4 va = blur7(c0, c1, c2, c3, c4, c5, c6);
            float4 vb = blur7(c1, c2, c3, c4, c5, c6, c7);
            a0 = a1; a1 = a2; a2 = a3; a3 = a4; a4 = a5; a5 = a6; a6 = va;
            b0 = b1; b1 = b2; b2 = b3; b3 = b4; b4 = b5; b5 = b6; b6 = vb;
        }

        const int dout = din - 3;
        if (dout >= d0) {   // dout < d0+CHUNK by loop bound
            float4 oa = blur7(a0, a1, a2, a3, a4, a5, a6);
            float4 ob = blur7(b0, b1, b2, b3, b4, b5, b6);
            const size_t base = nbase + (size_t)dout * SLICE;
            out[base + (size_t)(h0 + 2 * hp + 0) * DIM + (w0 + lw)] = oa;
            out[base + (size_t)(h0 + 2 * hp + 1) * DIM + (w0 + lw)] = ob;
        }
    }
#undef PREFETCH
}

extern "C" void kernel_launch(void* const* d_in, const int* in_sizes, int n_in,
                              void* d_out, int out_size, void* d_ws, size_t ws_size,
                              hipStream_t stream) {
    const float4* in = (const float4*)d_in[0];
    float4* out = (float4*)d_out;
    const int nblocks =
        2 * (DIM / THT) * (DIM / TWT) * (DIM / CHUNK);  // 2*10*5*16 = 1600
    gauss3d_fused<<<nblocks, 256, 0, stream>>>(in, out);
}